// Round 1
// baseline (989.371 us; speedup 1.0000x reference)
//
#include <hip/hip_runtime.h>
#include <stdint.h>

#define T_TOK 8192
#define H_DIM 2048
#define F_DIM 1408
#define E_NUM 8
#define GU_DIM 2816   /* 2F */
#define NSLOT 16384   /* T * top_k */

typedef short bf16x8 __attribute__((ext_vector_type(8)));
typedef float f32x4 __attribute__((ext_vector_type(4)));

__device__ __forceinline__ unsigned short f2bf(float f) {
  union { float f; unsigned u; } v; v.f = f;
  unsigned r = v.u + 0x7fffu + ((v.u >> 16) & 1u);
  return (unsigned short)(r >> 16);
}
__device__ __forceinline__ float bf2f(unsigned short h) {
  union { unsigned u; float f; } v; v.u = ((unsigned)h) << 16;
  return v.f;
}

__device__ __forceinline__ void gload16(const unsigned short* g, unsigned short* l) {
  __builtin_amdgcn_global_load_lds(
      (const __attribute__((address_space(1))) unsigned int*)g,
      (__attribute__((address_space(3))) unsigned int*)l, 16, 0, 0);
}

/* ---------------- cast fp32 -> bf16, vectorized x4 ---------------- */
__global__ void cast_kernel(const float* __restrict__ in,
                            unsigned short* __restrict__ out, long n4) {
  long i = (long)blockIdx.x * blockDim.x + threadIdx.x;
  long stride = (long)gridDim.x * blockDim.x;
  for (; i < n4; i += stride) {
    float4 f = ((const float4*)in)[i];
    ushort4 o;
    o.x = f2bf(f.x); o.y = f2bf(f.y); o.z = f2bf(f.z); o.w = f2bf(f.w);
    ((ushort4*)out)[i] = o;
  }
}

/* ---------------- router: softmax top-2 + counts ---------------- */
__global__ void router_kernel(const float* __restrict__ logits,
                              int* __restrict__ counts,
                              int* __restrict__ tok_e, float* __restrict__ tok_w) {
  int t = blockIdx.x * blockDim.x + threadIdx.x;
  if (t >= T_TOK) return;
  float l[E_NUM];
  float4 a = ((const float4*)logits)[(size_t)t * 2];
  float4 b = ((const float4*)logits)[(size_t)t * 2 + 1];
  l[0]=a.x; l[1]=a.y; l[2]=a.z; l[3]=a.w;
  l[4]=b.x; l[5]=b.y; l[6]=b.z; l[7]=b.w;
  int i0 = 0; float m0v = l[0];
  #pragma unroll
  for (int e = 1; e < E_NUM; ++e) if (l[e] > m0v) { m0v = l[e]; i0 = e; }
  int i1 = -1; float m1v = -3.0e38f;
  #pragma unroll
  for (int e = 0; e < E_NUM; ++e) if (e != i0 && l[e] > m1v) { m1v = l[e]; i1 = e; }
  // normalized top-2 softmax == softmax over {l_i0, l_i1}
  float e1 = __expf(m1v - m0v);
  float inv = 1.0f / (1.0f + e1);
  tok_e[2*t]   = i0; tok_w[2*t]   = inv;
  tok_e[2*t+1] = i1; tok_w[2*t+1] = e1 * inv;
  atomicAdd(&counts[i0], 1);
  atomicAdd(&counts[i1], 1);
}

__global__ void scan_kernel(const int* __restrict__ counts,
                            int* __restrict__ offsets, int* __restrict__ cursors) {
  if (threadIdx.x == 0 && blockIdx.x == 0) {
    int o = 0;
    for (int e = 0; e < E_NUM; ++e) { offsets[e] = o; cursors[e] = o; o += counts[e]; }
  }
}

__global__ void scatter_kernel(const int* __restrict__ tok_e, const float* __restrict__ tok_w,
                               int* __restrict__ cursors,
                               int* __restrict__ token_ids, float* __restrict__ slot_w) {
  int t = blockIdx.x * blockDim.x + threadIdx.x;
  if (t >= T_TOK) return;
  #pragma unroll
  for (int j = 0; j < 2; ++j) {
    int e = tok_e[2*t+j];
    int slot = atomicAdd(&cursors[e], 1);
    token_ids[slot] = t;
    slot_w[slot] = tok_w[2*t+j];
  }
}

/* ---------------- tiled bf16 MFMA GEMM, C = A * B^T ----------------
 * BM=BN=128, BK=64, 256 threads (4 waves, 2x2 of 64x64), 16x16x32 mfma.
 * GATHER: A rows indirected through token_ids (GEMM1) vs compact (GEMM2).
 * EPI_ATOMIC: store bf16 GU (GEMM1) vs scaled fp32 atomicAdd into out (GEMM2).
 */
template <int K, bool GATHER, bool EPI_ATOMIC>
__global__ __launch_bounds__(256, 2)
void gemm_kernel(const unsigned short* __restrict__ A,
                 const unsigned short* __restrict__ B,
                 const int* __restrict__ counts, const int* __restrict__ offsets,
                 const int* __restrict__ token_ids, const float* __restrict__ slot_w,
                 unsigned short* __restrict__ GU, float* __restrict__ out,
                 long bstride_e) {
  const int e = blockIdx.z;
  const int count = counts[e];
  const int m0 = blockIdx.y * 128;
  if (m0 >= count) return;
  const int n0 = blockIdx.x * 128;
  const int off = offsets[e];
  const unsigned short* Bexp = B + (size_t)e * bstride_e;

  __shared__ __align__(16) unsigned short As[128 * 64];
  __shared__ __align__(16) unsigned short Bs[128 * 64];

  const int t = threadIdx.x;
  const int w = t >> 6, lane = t & 63;
  const int wm = w >> 1, wn = w & 1;
  const int quad = lane >> 4, col = lane & 15;

  // staging: chunk c = i*256 + t covers row c/8, 16B-chunk c%8 of a 128x64 tile
  const int colb = (t & 7) * 8;
  const unsigned short* aptr[4];
  const unsigned short* bptr[4];
  #pragma unroll
  for (int i = 0; i < 4; ++i) {
    int r = i * 32 + (t >> 3);
    int mr = m0 + r;
    if (GATHER) {
      int tok = (mr < count) ? token_ids[off + mr] : 0;
      aptr[i] = A + (size_t)tok * K + colb;
    } else {
      int row = (mr < count) ? (off + mr) : 0;
      aptr[i] = A + (size_t)row * K + colb;
    }
    bptr[i] = Bexp + (size_t)(n0 + r) * K + colb;
  }

  const f32x4 zero = {0.f, 0.f, 0.f, 0.f};
  f32x4 acc[4][4];
  #pragma unroll
  for (int tm = 0; tm < 4; ++tm)
    #pragma unroll
    for (int tn = 0; tn < 4; ++tn) acc[tm][tn] = zero;

  for (int k0 = 0; k0 < K; k0 += 64) {
    #pragma unroll
    for (int i = 0; i < 4; ++i) {
      gload16(aptr[i] + k0, &As[i * 2048 + w * 512]);
      gload16(bptr[i] + k0, &Bs[i * 2048 + w * 512]);
    }
    __syncthreads();
    #pragma unroll
    for (int ks = 0; ks < 2; ++ks) {
      bf16x8 af[4], bfr[4];
      #pragma unroll
      for (int tm = 0; tm < 4; ++tm)
        af[tm] = *(const bf16x8*)&As[(wm * 64 + tm * 16 + col) * 64 + ks * 32 + quad * 8];
      #pragma unroll
      for (int tn = 0; tn < 4; ++tn)
        bfr[tn] = *(const bf16x8*)&Bs[(wn * 64 + tn * 16 + col) * 64 + ks * 32 + quad * 8];
      #pragma unroll
      for (int tm = 0; tm < 4; ++tm)
        #pragma unroll
        for (int tn = 0; tn < 4; ++tn)
          acc[tm][tn] = __builtin_amdgcn_mfma_f32_16x16x32_bf16(af[tm], bfr[tn], acc[tm][tn], 0, 0, 0);
    }
    __syncthreads();
  }

  // epilogue: C/D layout col=lane&15, row=quad*4+reg (m89-verified)
  if (!EPI_ATOMIC) {
    #pragma unroll
    for (int tm = 0; tm < 4; ++tm)
      #pragma unroll
      for (int reg = 0; reg < 4; ++reg) {
        int m_l = wm * 64 + tm * 16 + quad * 4 + reg;
        if (m0 + m_l < count) {
          size_t rowoff = (size_t)(off + m0 + m_l) * GU_DIM + n0 + wn * 64;
          #pragma unroll
          for (int tn = 0; tn < 4; ++tn)
            GU[rowoff + tn * 16 + col] = f2bf(acc[tm][tn][reg]);
        }
      }
  } else {
    #pragma unroll
    for (int tm = 0; tm < 4; ++tm)
      #pragma unroll
      for (int reg = 0; reg < 4; ++reg) {
        int m_l = wm * 64 + tm * 16 + quad * 4 + reg;
        if (m0 + m_l < count) {
          int slot = off + m0 + m_l;
          int tok = token_ids[slot];
          float wv = slot_w[slot];
          float* orow = out + (size_t)tok * H_DIM + n0 + wn * 64;
          #pragma unroll
          for (int tn = 0; tn < 4; ++tn)
            atomicAdd(&orow[tn * 16 + col], wv * acc[tm][tn][reg]);
        }
      }
  }
}

/* ---------------- silu(gate) * up ---------------- */
__global__ void silu_kernel(const unsigned short* __restrict__ GU,
                            unsigned short* __restrict__ Hb) {
  const long total4 = (long)NSLOT * (F_DIM / 4);
  long i = (long)blockIdx.x * blockDim.x + threadIdx.x;
  long stride = (long)gridDim.x * blockDim.x;
  for (; i < total4; i += stride) {
    long s = i / (F_DIM / 4);
    int f4 = (int)(i % (F_DIM / 4));
    const unsigned short* grow = GU + (size_t)s * GU_DIM;
    ushort4 g = ((const ushort4*)grow)[f4];
    ushort4 u = ((const ushort4*)(grow + F_DIM))[f4];
    ushort4 o;
    float gv, hv;
    gv = bf2f(g.x); hv = gv / (1.f + __expf(-gv)) * bf2f(u.x); o.x = f2bf(hv);
    gv = bf2f(g.y); hv = gv / (1.f + __expf(-gv)) * bf2f(u.y); o.y = f2bf(hv);
    gv = bf2f(g.z); hv = gv / (1.f + __expf(-gv)) * bf2f(u.z); o.z = f2bf(hv);
    gv = bf2f(g.w); hv = gv / (1.f + __expf(-gv)) * bf2f(u.w); o.w = f2bf(hv);
    ((ushort4*)(Hb + (size_t)s * F_DIM))[f4] = o;
  }
}

extern "C" void kernel_launch(void* const* d_in, const int* in_sizes, int n_in,
                              void* d_out, int out_size, void* d_ws, size_t ws_size,
                              hipStream_t stream) {
  const float* hidden = (const float*)d_in[0];
  const float* rlog   = (const float*)d_in[1];
  const float* w1     = (const float*)d_in[2];
  const float* w2     = (const float*)d_in[3];
  float* out = (float*)d_out;
  char* ws = (char*)d_ws;

  size_t o = 0;
  auto take = [&](size_t bytes) { size_t r = o; o += (bytes + 255) & ~(size_t)255; return r; };
  unsigned short* Xbf  = (unsigned short*)(ws + take((size_t)T_TOK * H_DIM * 2));
  unsigned short* W1bf = (unsigned short*)(ws + take((size_t)E_NUM * GU_DIM * H_DIM * 2));
  unsigned short* W2bf = (unsigned short*)(ws + take((size_t)E_NUM * H_DIM * F_DIM * 2));
  unsigned short* GU   = (unsigned short*)(ws + take((size_t)NSLOT * GU_DIM * 2));
  unsigned short* Hb   = (unsigned short*)(ws + take((size_t)NSLOT * F_DIM * 2));
  size_t ctrl_off = take(256 * 3);           // counts / offsets / cursors
  int* counts  = (int*)(ws + ctrl_off);
  int* offsets = (int*)(ws + ctrl_off + 256);
  int* cursors = (int*)(ws + ctrl_off + 512);
  int*   tok_e     = (int*)(ws + take((size_t)T_TOK * 2 * 4));
  float* tok_w     = (float*)(ws + take((size_t)T_TOK * 2 * 4));
  int*   token_ids = (int*)(ws + take((size_t)NSLOT * 4));
  float* slot_w    = (float*)(ws + take((size_t)NSLOT * 4));

  hipMemsetAsync(ws + ctrl_off, 0, 256 * 3, stream);
  hipMemsetAsync(out, 0, (size_t)T_TOK * H_DIM * sizeof(float), stream);

  cast_kernel<<<2048, 256, 0, stream>>>(hidden, Xbf, (long)T_TOK * H_DIM / 4);
  cast_kernel<<<4096, 256, 0, stream>>>(w1, W1bf, (long)E_NUM * GU_DIM * H_DIM / 4);
  cast_kernel<<<4096, 256, 0, stream>>>(w2, W2bf, (long)E_NUM * H_DIM * F_DIM / 4);

  router_kernel<<<T_TOK / 256, 256, 0, stream>>>(rlog, counts, tok_e, tok_w);
  scan_kernel<<<1, 64, 0, stream>>>(counts, offsets, cursors);
  scatter_kernel<<<T_TOK / 256, 256, 0, stream>>>(tok_e, tok_w, cursors, token_ids, slot_w);

  dim3 g1(GU_DIM / 128, T_TOK / 128, E_NUM);
  gemm_kernel<H_DIM, true, false><<<g1, 256, 0, stream>>>(
      Xbf, W1bf, counts, offsets, token_ids, slot_w, GU, nullptr,
      (long)GU_DIM * H_DIM);

  silu_kernel<<<4096, 256, 0, stream>>>(GU, Hb);

  dim3 g2(H_DIM / 128, T_TOK / 128, E_NUM);
  gemm_kernel<F_DIM, false, true><<<g2, 256, 0, stream>>>(
      Hb, W2bf, counts, offsets, token_ids, slot_w, nullptr, out,
      (long)H_DIM * F_DIM);
}

// Round 2
// 882.821 us; speedup vs baseline: 1.1207x; 1.1207x over previous
//
#include <hip/hip_runtime.h>
#include <stdint.h>

#define T_TOK 8192
#define H_DIM 2048
#define F_DIM 1408
#define E_NUM 8
#define GU_DIM 2816   /* 2F */
#define NSLOT 16384   /* T * top_k */

typedef short bf16x8 __attribute__((ext_vector_type(8)));
typedef float f32x4 __attribute__((ext_vector_type(4)));

__device__ __forceinline__ unsigned short f2bf(float f) {
  union { float f; unsigned u; } v; v.f = f;
  unsigned r = v.u + 0x7fffu + ((v.u >> 16) & 1u);
  return (unsigned short)(r >> 16);
}
__device__ __forceinline__ float bf2f(unsigned short h) {
  union { unsigned u; float f; } v; v.u = ((unsigned)h) << 16;
  return v.f;
}

__device__ __forceinline__ void gload16(const unsigned short* g, unsigned short* l) {
  __builtin_amdgcn_global_load_lds(
      (const __attribute__((address_space(1))) unsigned int*)g,
      (__attribute__((address_space(3))) unsigned int*)l, 16, 0, 0);
}

/* ---------------- cast fp32 -> bf16, vectorized x4 ---------------- */
__global__ void cast_kernel(const float* __restrict__ in,
                            unsigned short* __restrict__ out, long n4) {
  long i = (long)blockIdx.x * blockDim.x + threadIdx.x;
  long stride = (long)gridDim.x * blockDim.x;
  for (; i < n4; i += stride) {
    float4 f = ((const float4*)in)[i];
    ushort4 o;
    o.x = f2bf(f.x); o.y = f2bf(f.y); o.z = f2bf(f.z); o.w = f2bf(f.w);
    ((ushort4*)out)[i] = o;
  }
}

/* cast w1 with gate/up row interleave:
 * dst row n (within expert): group=n>>5, within=n&31, f=group*16+(within&15)
 * src row = (within<16) ? f : F_DIM+f.
 * => GEMM1 columns n and n+16 (within each 32-group) are gate_f and up_f. */
__global__ void cast_w1_kernel(const float* __restrict__ w1,
                               unsigned short* __restrict__ W1bf) {
  const long n4tot = (long)E_NUM * GU_DIM * (H_DIM / 4);
  long i = (long)blockIdx.x * blockDim.x + threadIdx.x;
  long stride = (long)gridDim.x * blockDim.x;
  for (; i < n4tot; i += stride) {
    int h4 = (int)(i & (H_DIM / 4 - 1));      // 512 per row, pow2
    long rn = i >> 9;
    int n = (int)(rn % GU_DIM);
    int e = (int)(rn / GU_DIM);
    int group = n >> 5, within = n & 31;
    int f = group * 16 + (within & 15);
    int src = (within < 16) ? f : (F_DIM + f);
    float4 v = ((const float4*)w1)[((long)e * GU_DIM + src) * (H_DIM / 4) + h4];
    ushort4 o;
    o.x = f2bf(v.x); o.y = f2bf(v.y); o.z = f2bf(v.z); o.w = f2bf(v.w);
    ((ushort4*)W1bf)[i] = o;
  }
}

/* ---------------- router: softmax top-2 + counts ---------------- */
__global__ void router_kernel(const float* __restrict__ logits,
                              int* __restrict__ counts,
                              int* __restrict__ tok_e, float* __restrict__ tok_w) {
  int t = blockIdx.x * blockDim.x + threadIdx.x;
  if (t >= T_TOK) return;
  float l[E_NUM];
  float4 a = ((const float4*)logits)[(size_t)t * 2];
  float4 b = ((const float4*)logits)[(size_t)t * 2 + 1];
  l[0]=a.x; l[1]=a.y; l[2]=a.z; l[3]=a.w;
  l[4]=b.x; l[5]=b.y; l[6]=b.z; l[7]=b.w;
  int i0 = 0; float m0v = l[0];
  #pragma unroll
  for (int e = 1; e < E_NUM; ++e) if (l[e] > m0v) { m0v = l[e]; i0 = e; }
  int i1 = -1; float m1v = -3.0e38f;
  #pragma unroll
  for (int e = 0; e < E_NUM; ++e) if (e != i0 && l[e] > m1v) { m1v = l[e]; i1 = e; }
  float e1 = __expf(m1v - m0v);
  float inv = 1.0f / (1.0f + e1);
  tok_e[2*t]   = i0; tok_w[2*t]   = inv;
  tok_e[2*t+1] = i1; tok_w[2*t+1] = e1 * inv;
  atomicAdd(&counts[i0], 1);
  atomicAdd(&counts[i1], 1);
}

__global__ void scan_kernel(const int* __restrict__ counts,
                            int* __restrict__ offsets, int* __restrict__ cursors) {
  if (threadIdx.x == 0 && blockIdx.x == 0) {
    int o = 0;
    for (int e = 0; e < E_NUM; ++e) { offsets[e] = o; cursors[e] = o; o += counts[e]; }
  }
}

__global__ void scatter_kernel(const int* __restrict__ tok_e, const float* __restrict__ tok_w,
                               int* __restrict__ cursors,
                               int* __restrict__ token_ids, float* __restrict__ slot_w,
                               int* __restrict__ slot_of) {
  int t = blockIdx.x * blockDim.x + threadIdx.x;
  if (t >= T_TOK) return;
  #pragma unroll
  for (int j = 0; j < 2; ++j) {
    int e = tok_e[2*t+j];
    int slot = atomicAdd(&cursors[e], 1);
    token_ids[slot] = t;
    slot_w[slot] = tok_w[2*t+j];
    slot_of[2*t+j] = slot;
  }
}

/* ---------------- tiled bf16 MFMA GEMM, C = A * B^T ----------------
 * BM=BN=128, BK=64, 256 threads (4 waves, 2x2 of 64x64), 16x16x32 mfma.
 * LDS tile is XOR-swizzled in 16B chunks: slot (r, c) holds global chunk
 * (r, c ^ (r&7)) -> quad-group ds_read_b128 spreads over all 32 banks
 * (2-way only, free per m136) instead of 16-way on one 4-bank group.
 * GATHER: A rows via token_ids (GEMM1) vs compact (GEMM2).
 * EPI 0: fused silu(gate)*up -> Hb bf16 (w1 rows pre-interleaved).
 * EPI 1: Y[slot] = slot_w * acc, bf16 store (combined later).
 */
template <int K, bool GATHER, int EPI>
__global__ __launch_bounds__(256, 2)
void gemm_kernel(const unsigned short* __restrict__ A,
                 const unsigned short* __restrict__ B,
                 const int* __restrict__ counts, const int* __restrict__ offsets,
                 const int* __restrict__ token_ids, const float* __restrict__ slot_w,
                 unsigned short* __restrict__ OutB, long bstride_e) {
  const int e = blockIdx.z;
  const int count = counts[e];
  const int m0 = blockIdx.y * 128;
  if (m0 >= count) return;
  const int n0 = blockIdx.x * 128;
  const int off = offsets[e];
  const unsigned short* Bexp = B + (size_t)e * bstride_e;

  __shared__ __align__(16) unsigned short As[128 * 64];
  __shared__ __align__(16) unsigned short Bs[128 * 64];

  const int t = threadIdx.x;
  const int w = t >> 6, lane = t & 63;
  const int wm = w >> 1, wn = w & 1;
  const int quad = lane >> 4, col = lane & 15;

  // staging: lane covers row r = i*32 + t/8; its LDS chunk-col is t&7, so it
  // must fetch global chunk (t&7) ^ (r&7); r&7 == (t>>3)&7.
  const int colb = (((t & 7) ^ ((t >> 3) & 7)) * 8);
  const unsigned short* aptr[4];
  const unsigned short* bptr[4];
  #pragma unroll
  for (int i = 0; i < 4; ++i) {
    int r = i * 32 + (t >> 3);
    int mr = m0 + r;
    if (GATHER) {
      int tok = (mr < count) ? token_ids[off + mr] : 0;
      aptr[i] = A + (size_t)tok * K + colb;
    } else {
      int row = (mr < count) ? (off + mr) : 0;
      aptr[i] = A + (size_t)row * K + colb;
    }
    bptr[i] = Bexp + (size_t)(n0 + r) * K + colb;
  }

  const f32x4 zero = {0.f, 0.f, 0.f, 0.f};
  f32x4 acc[4][4];
  #pragma unroll
  for (int tm = 0; tm < 4; ++tm)
    #pragma unroll
    for (int tn = 0; tn < 4; ++tn) acc[tm][tn] = zero;

  const int sw = col & 7;  // (row & 7) for all fragment rows this lane reads

  for (int k0 = 0; k0 < K; k0 += 64) {
    #pragma unroll
    for (int i = 0; i < 4; ++i) {
      gload16(aptr[i] + k0, &As[i * 2048 + w * 512]);
      gload16(bptr[i] + k0, &Bs[i * 2048 + w * 512]);
    }
    __syncthreads();
    #pragma unroll
    for (int ks = 0; ks < 2; ++ks) {
      const int c = ks * 4 + quad;
      const int coff = (c ^ sw) * 8;
      bf16x8 af[4], bfr[4];
      #pragma unroll
      for (int tm = 0; tm < 4; ++tm)
        af[tm] = *(const bf16x8*)&As[(wm * 64 + tm * 16 + col) * 64 + coff];
      #pragma unroll
      for (int tn = 0; tn < 4; ++tn)
        bfr[tn] = *(const bf16x8*)&Bs[(wn * 64 + tn * 16 + col) * 64 + coff];
      #pragma unroll
      for (int tm = 0; tm < 4; ++tm)
        #pragma unroll
        for (int tn = 0; tn < 4; ++tn)
          acc[tm][tn] = __builtin_amdgcn_mfma_f32_16x16x32_bf16(af[tm], bfr[tn], acc[tm][tn], 0, 0, 0);
    }
    __syncthreads();
  }

  // C/D layout: col = lane&15, row = quad*4 + reg (m89-verified)
  if (EPI == 0) {
    // columns n and n+16 of each 32-group are gate_f / up_f, f = n/32*16 + col
    const int fbase = (n0 + wn * 64) >> 1;   // == (B/32)*16
    #pragma unroll
    for (int tm = 0; tm < 4; ++tm)
      #pragma unroll
      for (int reg = 0; reg < 4; ++reg) {
        int m_l = wm * 64 + tm * 16 + quad * 4 + reg;
        if (m0 + m_l < count) {
          unsigned short* hrow = OutB + (size_t)(off + m0 + m_l) * F_DIM + fbase + col;
          float g0 = acc[tm][0][reg], u0 = acc[tm][1][reg];
          float g1 = acc[tm][2][reg], u1 = acc[tm][3][reg];
          hrow[0]  = f2bf(g0 / (1.f + __expf(-g0)) * u0);
          hrow[16] = f2bf(g1 / (1.f + __expf(-g1)) * u1);
        }
      }
  } else {
    #pragma unroll
    for (int tm = 0; tm < 4; ++tm)
      #pragma unroll
      for (int reg = 0; reg < 4; ++reg) {
        int m_l = wm * 64 + tm * 16 + quad * 4 + reg;
        if (m0 + m_l < count) {
          int slot = off + m0 + m_l;
          float wv = slot_w[slot];
          unsigned short* yrow = OutB + (size_t)slot * H_DIM + n0 + wn * 64;
          #pragma unroll
          for (int tn = 0; tn < 4; ++tn)
            yrow[tn * 16 + col] = f2bf(wv * acc[tm][tn][reg]);
        }
      }
  }
}

/* ---------------- out[t] = Y[s0(t)] + Y[s1(t)] ---------------- */
__global__ void combine_kernel(const unsigned short* __restrict__ Y,
                               const int* __restrict__ slot_of,
                               float* __restrict__ out) {
  const long n4 = (long)T_TOK * (H_DIM / 4);
  long i = (long)blockIdx.x * blockDim.x + threadIdx.x;
  long stride = (long)gridDim.x * blockDim.x;
  for (; i < n4; i += stride) {
    int h4 = (int)(i & (H_DIM / 4 - 1));
    int t = (int)(i >> 9);
    int s0 = slot_of[2 * t], s1 = slot_of[2 * t + 1];
    ushort4 a = ((const ushort4*)(Y + (size_t)s0 * H_DIM))[h4];
    ushort4 b = ((const ushort4*)(Y + (size_t)s1 * H_DIM))[h4];
    float4 o;
    o.x = bf2f(a.x) + bf2f(b.x);
    o.y = bf2f(a.y) + bf2f(b.y);
    o.z = bf2f(a.z) + bf2f(b.z);
    o.w = bf2f(a.w) + bf2f(b.w);
    ((float4*)out)[i] = o;
  }
}

extern "C" void kernel_launch(void* const* d_in, const int* in_sizes, int n_in,
                              void* d_out, int out_size, void* d_ws, size_t ws_size,
                              hipStream_t stream) {
  const float* hidden = (const float*)d_in[0];
  const float* rlog   = (const float*)d_in[1];
  const float* w1     = (const float*)d_in[2];
  const float* w2     = (const float*)d_in[3];
  float* out = (float*)d_out;
  char* ws = (char*)d_ws;

  size_t o = 0;
  auto take = [&](size_t bytes) { size_t r = o; o += (bytes + 255) & ~(size_t)255; return r; };
  unsigned short* Xbf  = (unsigned short*)(ws + take((size_t)T_TOK * H_DIM * 2));
  unsigned short* W1bf = (unsigned short*)(ws + take((size_t)E_NUM * GU_DIM * H_DIM * 2));
  unsigned short* W2bf = (unsigned short*)(ws + take((size_t)E_NUM * H_DIM * F_DIM * 2));
  unsigned short* Hb   = (unsigned short*)(ws + take((size_t)NSLOT * F_DIM * 2));
  unsigned short* Y    = (unsigned short*)(ws + take((size_t)NSLOT * H_DIM * 2));
  size_t ctrl_off = take(256 * 3);           // counts / offsets / cursors
  int* counts  = (int*)(ws + ctrl_off);
  int* offsets = (int*)(ws + ctrl_off + 256);
  int* cursors = (int*)(ws + ctrl_off + 512);
  int*   tok_e     = (int*)(ws + take((size_t)T_TOK * 2 * 4));
  float* tok_w     = (float*)(ws + take((size_t)T_TOK * 2 * 4));
  int*   token_ids = (int*)(ws + take((size_t)NSLOT * 4));
  float* slot_w    = (float*)(ws + take((size_t)NSLOT * 4));
  int*   slot_of   = (int*)(ws + take((size_t)NSLOT * 4));

  hipMemsetAsync(ws + ctrl_off, 0, 256 * 3, stream);

  cast_kernel<<<2048, 256, 0, stream>>>(hidden, Xbf, (long)T_TOK * H_DIM / 4);
  cast_w1_kernel<<<4096, 256, 0, stream>>>(w1, W1bf);
  cast_kernel<<<4096, 256, 0, stream>>>(w2, W2bf, (long)E_NUM * H_DIM * F_DIM / 4);

  router_kernel<<<T_TOK / 256, 256, 0, stream>>>(rlog, counts, tok_e, tok_w);
  scan_kernel<<<1, 64, 0, stream>>>(counts, offsets, cursors);
  scatter_kernel<<<T_TOK / 256, 256, 0, stream>>>(tok_e, tok_w, cursors,
                                                  token_ids, slot_w, slot_of);

  dim3 g1(GU_DIM / 128, T_TOK / 128, E_NUM);
  gemm_kernel<H_DIM, true, 0><<<g1, 256, 0, stream>>>(
      Xbf, W1bf, counts, offsets, token_ids, slot_w, Hb,
      (long)GU_DIM * H_DIM);

  dim3 g2(H_DIM / 128, T_TOK / 128, E_NUM);
  gemm_kernel<F_DIM, false, 1><<<g2, 256, 0, stream>>>(
      Hb, W2bf, counts, offsets, token_ids, slot_w, Y,
      (long)H_DIM * F_DIM);

  combine_kernel<<<4096, 256, 0, stream>>>(Y, slot_of, out);
}